// Round 4
// baseline (544.687 us; speedup 1.0000x reference)
//
#include <hip/hip_runtime.h>

typedef short short8 __attribute__((ext_vector_type(8)));
typedef float f32x4 __attribute__((ext_vector_type(4)));

#define HDIM 128
#define SCAN_NB 256
#define SCAN_TPB 256

__device__ __forceinline__ ushort f2bf(float f) {
  uint u = __float_as_uint(f);
  u += 0x7fffu + ((u >> 16) & 1u);   // round-to-nearest-even
  return (ushort)(u >> 16);
}
__device__ __forceinline__ float bflo(uint v){ return __uint_as_float(v << 16); }
__device__ __forceinline__ float bfhi(uint v){ return __uint_as_float(v & 0xffff0000u); }

// ---------------- degree count over dst ----------------
__global__ __launch_bounds__(256) void k_deg(const int* __restrict__ dst, int E, int* __restrict__ degc) {
  for (int e = blockIdx.x*blockDim.x + threadIdx.x; e < E; e += gridDim.x*blockDim.x)
    atomicAdd(&degc[dst[e]], 1);
}

// ---------------- dinv = rsqrt(deg+1) ----------------
__global__ __launch_bounds__(256) void k_dinv(const int* __restrict__ degc, float* __restrict__ dinv, int N) {
  int i = blockIdx.x*256 + threadIdx.x;
  if (i < N) dinv[i] = rsqrtf((float)degc[i] + 1.0f);
}

// ---------------- hierarchical scan: phase A (block partial sums) ----------------
__global__ __launch_bounds__(SCAN_TPB) void k_scanA(const int* __restrict__ degc, int N,
                                                    int* __restrict__ blocksum) {
  int ipt = (N + SCAN_NB*SCAN_TPB - 1) / (SCAN_NB*SCAN_TPB);  // <= 4 for N <= 262144
  int chunk = ipt * SCAN_TPB;
  int start = blockIdx.x * chunk + threadIdx.x * ipt;
  int s = 0;
  #pragma unroll
  for (int k = 0; k < 4; ++k) {
    if (k < ipt) { int i = start + k; if (i < N) s += degc[i]; }
  }
  __shared__ int red[SCAN_TPB];
  int t = threadIdx.x;
  red[t] = s; __syncthreads();
  for (int off = SCAN_TPB/2; off > 0; off >>= 1) {
    if (t < off) red[t] += red[t+off];
    __syncthreads();
  }
  if (t == 0) blocksum[blockIdx.x] = red[0];
}

// ---------------- phase B: scan the block sums (single tiny block) ----------------
__global__ __launch_bounds__(SCAN_NB) void k_scanB(const int* __restrict__ blocksum,
                                                   int* __restrict__ blockoff, int* __restrict__ totalN) {
  __shared__ int sh[SCAN_NB];
  int t = threadIdx.x;
  sh[t] = blocksum[t];
  __syncthreads();
  for (int off = 1; off < SCAN_NB; off <<= 1) {
    int v = (t >= off) ? sh[t-off] : 0;
    __syncthreads();
    sh[t] += v;
    __syncthreads();
  }
  blockoff[t] = (t == 0) ? 0 : sh[t-1];
  if (t == SCAN_NB-1) *totalN = sh[t];
}

// ---------------- phase C: local exclusive scan + block offset -> row_ptr ----------------
__global__ __launch_bounds__(SCAN_TPB) void k_scanC(const int* __restrict__ degc, int N,
    const int* __restrict__ blockoff, const int* __restrict__ totalN, int* __restrict__ row_ptr) {
  int ipt = (N + SCAN_NB*SCAN_TPB - 1) / (SCAN_NB*SCAN_TPB);
  int chunk = ipt * SCAN_TPB;
  int start = blockIdx.x * chunk + threadIdx.x * ipt;
  int t = threadIdx.x;
  int vals[4];
  int s = 0;
  #pragma unroll
  for (int k = 0; k < 4; ++k) {
    int v = 0;
    if (k < ipt) { int i = start + k; if (i < N) v = degc[i]; }
    vals[k] = v; s += v;
  }
  __shared__ int sh[SCAN_TPB];
  sh[t] = s; __syncthreads();
  for (int off = 1; off < SCAN_TPB; off <<= 1) {
    int v = (t >= off) ? sh[t-off] : 0;
    __syncthreads();
    sh[t] += v;
    __syncthreads();
  }
  int run = blockoff[blockIdx.x] + ((t == 0) ? 0 : sh[t-1]);
  #pragma unroll
  for (int k = 0; k < 4; ++k) {
    if (k < ipt) { int i = start + k; if (i < N) row_ptr[i] = run; }
    run += vals[k];
  }
  if (blockIdx.x == 0 && t == 0) row_ptr[N] = *totalN;
}

// ---------------- fill CSR: esrc[pos] = src (coef computed in k_agg) ----------------
__global__ __launch_bounds__(256) void k_fill(const int* __restrict__ src, const int* __restrict__ dst, int E,
    const int* __restrict__ row_ptr, int* __restrict__ fill, int* __restrict__ esrc) {
  for (int e = blockIdx.x*blockDim.x + threadIdx.x; e < E; e += gridDim.x*blockDim.x) {
    int s = src[e], d = dst[e];
    int pos = row_ptr[d] + atomicAdd(&fill[d], 1);
    esrc[pos] = s;
  }
}

// ---------------- GEMM: xw(bf16) = in @ W, bf16 MFMA 16x16x32 ----------------
template<int IN_F32>
__global__ __launch_bounds__(256,1) void k_gemm(const void* __restrict__ in_, const float* __restrict__ W,
    ushort* __restrict__ xw, int N) {
  int lane = threadIdx.x & 63;
  int wid  = (blockIdx.x * blockDim.x + threadIdx.x) >> 6;
  int nw   = (gridDim.x * blockDim.x) >> 6;
  int colB = lane & 15;
  int krow = (lane >> 4) * 8;

  short8 bfr[8][4];
  #pragma unroll
  for (int nt = 0; nt < 8; ++nt)
    #pragma unroll
    for (int kc = 0; kc < 4; ++kc) {
      short8 t;
      #pragma unroll
      for (int j = 0; j < 8; ++j)
        t[j] = (short)f2bf(W[(kc*32 + krow + j)*HDIM + nt*16 + colB]);
      bfr[nt][kc] = t;
    }

  int strips = (N + 15) >> 4;
  for (int s = wid; s < strips; s += nw) {
    int ra = s*16 + (lane & 15);
    bool va = ra < N;
    short8 a[4];
    if (IN_F32) {
      const float* xin = (const float*)in_;
      #pragma unroll
      for (int kc = 0; kc < 4; ++kc) {
        short8 t = {0,0,0,0,0,0,0,0};
        if (va) {
          const float* p = xin + (size_t)ra*HDIM + kc*32 + krow;
          float4 lo4 = *(const float4*)p;
          float4 hi4 = *(const float4*)(p+4);
          t[0]=(short)f2bf(lo4.x); t[1]=(short)f2bf(lo4.y); t[2]=(short)f2bf(lo4.z); t[3]=(short)f2bf(lo4.w);
          t[4]=(short)f2bf(hi4.x); t[5]=(short)f2bf(hi4.y); t[6]=(short)f2bf(hi4.z); t[7]=(short)f2bf(hi4.w);
        }
        a[kc] = t;
      }
    } else {
      const ushort* hin = (const ushort*)in_;
      #pragma unroll
      for (int kc = 0; kc < 4; ++kc) {
        short8 t = {0,0,0,0,0,0,0,0};
        if (va) t = *(const short8*)(hin + (size_t)ra*HDIM + kc*32 + krow);
        a[kc] = t;
      }
    }
    f32x4 acc[8];
    #pragma unroll
    for (int nt = 0; nt < 8; ++nt) { acc[nt][0]=0.f; acc[nt][1]=0.f; acc[nt][2]=0.f; acc[nt][3]=0.f; }
    #pragma unroll
    for (int nt = 0; nt < 8; ++nt)
      #pragma unroll
      for (int kc = 0; kc < 4; ++kc)
        acc[nt] = __builtin_amdgcn_mfma_f32_16x16x32_bf16(a[kc], bfr[nt][kc], acc[nt], 0, 0, 0);

    int r0 = s*16 + (lane>>4)*4;
    #pragma unroll
    for (int nt = 0; nt < 8; ++nt) {
      int c = nt*16 + (lane&15);
      #pragma unroll
      for (int rg = 0; rg < 4; ++rg) {
        int rr = r0 + rg;
        if (rr < N) xw[(size_t)rr*HDIM + c] = f2bf(acc[nt][rg]);
      }
    }
  }
}

// ---------------- aggregation: one wave per node, 16 gathers in flight ----------------
// esrc holds just src ids. coef = dinv[s]*dinv[n]; dinv[n] factored out of the sum.
// dinv[s] fetched via readlane->SGPR (s_load path, keeps VMEM queue for row gathers).
__global__ __launch_bounds__(256) void k_agg(const uint* __restrict__ xwu, const int* __restrict__ esrc,
    const int* __restrict__ row_ptr, const float* __restrict__ dinv, const float* __restrict__ bias,
    uint* __restrict__ hu, int N) {
  int lane = threadIdx.x & 63;
  int n = blockIdx.x*4 + (threadIdx.x >> 6);
  if (n >= N) return;
  int e0 = row_ptr[n], e1 = row_ptr[n+1];
  float dn = dinv[n];
  float a0 = 0.f, a1 = 0.f;
  for (int base = e0; base < e1; base += 64) {
    int cnt = min(64, e1 - base);
    int mys = (lane < cnt) ? esrc[base + lane] : 0;
    for (int j = 0; j < cnt; j += 16) {
      int sN[16]; float cf[16];
      #pragma unroll
      for (int u = 0; u < 16; ++u)
        sN[u] = __builtin_amdgcn_readlane(mys, j + u);
      #pragma unroll
      for (int u = 0; u < 16; ++u)
        cf[u] = (j + u < cnt) ? dinv[sN[u]] : 0.0f;
      #pragma unroll
      for (int u = 0; u < 16; ++u) {
        uint v = xwu[(size_t)sN[u]*64 + lane];
        a0 += cf[u] * bflo(v);
        a1 += cf[u] * bfhi(v);
      }
    }
  }
  // edge sum carried dinv[s] only; apply the common dinv[n] factor once.
  a0 *= dn; a1 *= dn;
  float w = dn*dn;
  uint v = xwu[(size_t)n*64 + lane];
  a0 += w * bflo(v);
  a1 += w * bfhi(v);
  a0 += bias[lane*2];  a1 += bias[lane*2+1];
  a0 = fmaxf(a0, 0.f); a1 = fmaxf(a1, 0.f);
  uint o = ((uint)f2bf(a0)) | (((uint)f2bf(a1)) << 16);
  hu[(size_t)n*64 + lane] = o;
}

// ---------------- pooling: segmented accumulate (batch sorted) ----------------
__global__ __launch_bounds__(256) void k_pool(const uint* __restrict__ hu, const int* __restrict__ batch,
    float* __restrict__ psum, int N) {
  int lane = threadIdx.x & 63;
  int wave = threadIdx.x >> 6;
  int n0 = blockIdx.x*512 + wave*128;
  if (n0 >= N) return;
  int n1 = min(n0 + 128, N);
  float a0 = 0.f, a1 = 0.f;
  int gc = batch[n0];
  for (int n = n0; n < n1; ++n) {
    int g = batch[n];
    if (g != gc) {
      atomicAdd(&psum[gc*HDIM + lane*2],   a0);
      atomicAdd(&psum[gc*HDIM + lane*2+1], a1);
      a0 = 0.f; a1 = 0.f; gc = g;
    }
    uint v = hu[(size_t)n*64 + lane];
    a0 += bflo(v); a1 += bfhi(v);
  }
  atomicAdd(&psum[gc*HDIM + lane*2],   a0);
  atomicAdd(&psum[gc*HDIM + lane*2+1], a1);
}

// ---------------- graph sizes via binary search (batch sorted) ----------------
__global__ void k_bounds(const int* __restrict__ batch, int N, int G, float* __restrict__ inv_cnt) {
  __shared__ int bnd[256];
  int g = threadIdx.x;
  if (g <= G) {
    int lo = 0, hi = N;
    while (lo < hi) { int mid = (lo + hi) >> 1; if (batch[mid] < g) lo = mid + 1; else hi = mid; }
    bnd[g] = lo;
  }
  __syncthreads();
  if (g < G) {
    int c = bnd[g+1] - bnd[g];
    inv_cnt[g] = 1.0f / (float)max(c, 1);
  }
}

// ---------------- final linear: out = (psum*inv) @ Wlin + blin ----------------
__global__ __launch_bounds__(256) void k_final(const float* __restrict__ psum, const float* __restrict__ inv_cnt,
    const float* __restrict__ Wlin, const float* __restrict__ blin, float* __restrict__ out, int G, int C) {
  int idx = blockIdx.x*256 + threadIdx.x;
  if (idx >= G*C) return;
  int g = idx / C, c = idx % C;
  float acc = 0.f;
  for (int k = 0; k < HDIM; ++k) acc += psum[g*HDIM + k] * Wlin[k*C + c];
  out[idx] = acc * inv_cnt[g] + blin[c];
}

extern "C" void kernel_launch(void* const* d_in, const int* in_sizes, int n_in,
                              void* d_out, int out_size, void* d_ws, size_t ws_size,
                              hipStream_t stream) {
  const float* x    = (const float*)d_in[0];
  const int*   ei   = (const int*)d_in[1];
  const int*   batch= (const int*)d_in[2];
  const float* W0   = (const float*)d_in[3];
  const float* b0   = (const float*)d_in[4];
  const float* W1   = (const float*)d_in[5];
  const float* b1   = (const float*)d_in[6];
  const float* W2   = (const float*)d_in[7];
  const float* b2   = (const float*)d_in[8];
  const float* Wlin = (const float*)d_in[9];
  const float* blin = (const float*)d_in[10];

  int N = in_sizes[0] / HDIM;
  int E = in_sizes[1] / 2;
  int C = in_sizes[10];
  int G = out_size / C;
  const int* src = ei;
  const int* dst = ei + E;

  char* ws = (char*)d_ws;
  size_t o = 0;
  auto alloc = [&](size_t bytes){ size_t r = o; o += (bytes + 511) & ~(size_t)511; return r; };
  // zero-init region first (one memset covers degc..psum including pad)
  size_t zbeg  = o;
  int*    degc    = (int*)   (ws + alloc((size_t)N*4));
  int*    fill    = (int*)   (ws + alloc((size_t)N*4));
  float*  psum    = (float*) (ws + alloc((size_t)G*HDIM*4));
  size_t zend  = o;
  float*  dinv    = (float*) (ws + alloc((size_t)N*4));
  int*    row_ptr = (int*)   (ws + alloc((size_t)(N+1)*4));
  float*  inv_cnt = (float*) (ws + alloc((size_t)G*4));
  int*    blocksum= (int*)   (ws + alloc((size_t)SCAN_NB*4));
  int*    blockoff= (int*)   (ws + alloc((size_t)SCAN_NB*4));
  int*    totalN  = (int*)   (ws + alloc(4));
  int*    esrc    = (int*)   (ws + alloc((size_t)E*4));
  ushort* xw      = (ushort*)(ws + alloc((size_t)N*HDIM*2));
  ushort* hbuf    = (ushort*)(ws + alloc((size_t)N*HDIM*2));

  hipMemsetAsync(ws + zbeg, 0, zend - zbeg, stream);

  k_deg  <<<2048, 256, 0, stream>>>(dst, E, degc);
  k_dinv <<<(N+255)/256, 256, 0, stream>>>(degc, dinv, N);
  k_scanA<<<SCAN_NB, SCAN_TPB, 0, stream>>>(degc, N, blocksum);
  k_scanB<<<1, SCAN_NB, 0, stream>>>(blocksum, blockoff, totalN);
  k_scanC<<<SCAN_NB, SCAN_TPB, 0, stream>>>(degc, N, blockoff, totalN, row_ptr);
  k_fill <<<2048, 256, 0, stream>>>(src, dst, E, row_ptr, fill, esrc);
  k_bounds<<<1, 256, 0, stream>>>(batch, N, G, inv_cnt);

  const int gemm_blocks = 512;
  const int agg_blocks  = (N + 3) / 4;

  // layer 0
  k_gemm<1><<<gemm_blocks, 256, 0, stream>>>((const void*)x, W0, xw, N);
  k_agg<<<agg_blocks, 256, 0, stream>>>((const uint*)xw, esrc, row_ptr, dinv, b0, (uint*)hbuf, N);
  // layer 1
  k_gemm<0><<<gemm_blocks, 256, 0, stream>>>((const void*)hbuf, W1, xw, N);
  k_agg<<<agg_blocks, 256, 0, stream>>>((const uint*)xw, esrc, row_ptr, dinv, b1, (uint*)hbuf, N);
  // layer 2
  k_gemm<0><<<gemm_blocks, 256, 0, stream>>>((const void*)hbuf, W2, xw, N);
  k_agg<<<agg_blocks, 256, 0, stream>>>((const uint*)xw, esrc, row_ptr, dinv, b2, (uint*)hbuf, N);

  k_pool<<<(N + 511)/512, 256, 0, stream>>>((const uint*)hbuf, batch, psum, N);
  k_final<<<(G*C + 255)/256, 256, 0, stream>>>(psum, inv_cnt, Wlin, blin, (float*)d_out, G, C);
}

// Round 5
// 438.727 us; speedup vs baseline: 1.2415x; 1.2415x over previous
//
#include <hip/hip_runtime.h>

typedef short short8 __attribute__((ext_vector_type(8)));
typedef float f32x4 __attribute__((ext_vector_type(4)));

#define HDIM 128
#define SCAN_NB 256
#define SCAN_TPB 256

__device__ __forceinline__ ushort f2bf(float f) {
  uint u = __float_as_uint(f);
  u += 0x7fffu + ((u >> 16) & 1u);   // round-to-nearest-even
  return (ushort)(u >> 16);
}
__device__ __forceinline__ float bflo(uint v){ return __uint_as_float(v << 16); }
__device__ __forceinline__ float bfhi(uint v){ return __uint_as_float(v & 0xffff0000u); }

// ---------------- degree count over dst ----------------
__global__ __launch_bounds__(256) void k_deg(const int* __restrict__ dst, int E, int* __restrict__ degc) {
  for (int e = blockIdx.x*blockDim.x + threadIdx.x; e < E; e += gridDim.x*blockDim.x)
    atomicAdd(&degc[dst[e]], 1);
}

// ---------------- dinv = rsqrt(deg+1) ----------------
__global__ __launch_bounds__(256) void k_dinv(const int* __restrict__ degc, float* __restrict__ dinv, int N) {
  int i = blockIdx.x*256 + threadIdx.x;
  if (i < N) dinv[i] = rsqrtf((float)degc[i] + 1.0f);
}

// ---------------- hierarchical scan ----------------
__global__ __launch_bounds__(SCAN_TPB) void k_scanA(const int* __restrict__ degc, int N,
                                                    int* __restrict__ blocksum) {
  int ipt = (N + SCAN_NB*SCAN_TPB - 1) / (SCAN_NB*SCAN_TPB);
  int chunk = ipt * SCAN_TPB;
  int start = blockIdx.x * chunk + threadIdx.x * ipt;
  int s = 0;
  #pragma unroll
  for (int k = 0; k < 4; ++k) {
    if (k < ipt) { int i = start + k; if (i < N) s += degc[i]; }
  }
  __shared__ int red[SCAN_TPB];
  int t = threadIdx.x;
  red[t] = s; __syncthreads();
  for (int off = SCAN_TPB/2; off > 0; off >>= 1) {
    if (t < off) red[t] += red[t+off];
    __syncthreads();
  }
  if (t == 0) blocksum[blockIdx.x] = red[0];
}

__global__ __launch_bounds__(SCAN_NB) void k_scanB(const int* __restrict__ blocksum,
                                                   int* __restrict__ blockoff, int* __restrict__ totalN) {
  __shared__ int sh[SCAN_NB];
  int t = threadIdx.x;
  sh[t] = blocksum[t];
  __syncthreads();
  for (int off = 1; off < SCAN_NB; off <<= 1) {
    int v = (t >= off) ? sh[t-off] : 0;
    __syncthreads();
    sh[t] += v;
    __syncthreads();
  }
  blockoff[t] = (t == 0) ? 0 : sh[t-1];
  if (t == SCAN_NB-1) *totalN = sh[t];
}

__global__ __launch_bounds__(SCAN_TPB) void k_scanC(const int* __restrict__ degc, int N,
    const int* __restrict__ blockoff, const int* __restrict__ totalN, int* __restrict__ row_ptr) {
  int ipt = (N + SCAN_NB*SCAN_TPB - 1) / (SCAN_NB*SCAN_TPB);
  int chunk = ipt * SCAN_TPB;
  int start = blockIdx.x * chunk + threadIdx.x * ipt;
  int t = threadIdx.x;
  int vals[4];
  int s = 0;
  #pragma unroll
  for (int k = 0; k < 4; ++k) {
    int v = 0;
    if (k < ipt) { int i = start + k; if (i < N) v = degc[i]; }
    vals[k] = v; s += v;
  }
  __shared__ int sh[SCAN_TPB];
  sh[t] = s; __syncthreads();
  for (int off = 1; off < SCAN_TPB; off <<= 1) {
    int v = (t >= off) ? sh[t-off] : 0;
    __syncthreads();
    sh[t] += v;
    __syncthreads();
  }
  int run = blockoff[blockIdx.x] + ((t == 0) ? 0 : sh[t-1]);
  #pragma unroll
  for (int k = 0; k < 4; ++k) {
    if (k < ipt) { int i = start + k; if (i < N) row_ptr[i] = run; }
    run += vals[k];
  }
  if (blockIdx.x == 0 && t == 0) row_ptr[N] = *totalN;
}

// ---------------- GEMM body (device fn): xw(bf16) = in @ W ----------------
template<int IN_F32>
__device__ __forceinline__ void gemm_body(const void* __restrict__ in_, const float* __restrict__ W,
    ushort* __restrict__ xw, int N, int wid, int nw) {
  int lane = threadIdx.x & 63;
  int colB = lane & 15;
  int krow = (lane >> 4) * 8;

  short8 bfr[8][4];
  #pragma unroll
  for (int nt = 0; nt < 8; ++nt)
    #pragma unroll
    for (int kc = 0; kc < 4; ++kc) {
      short8 t;
      #pragma unroll
      for (int j = 0; j < 8; ++j)
        t[j] = (short)f2bf(W[(kc*32 + krow + j)*HDIM + nt*16 + colB]);
      bfr[nt][kc] = t;
    }

  int strips = (N + 15) >> 4;
  for (int s = wid; s < strips; s += nw) {
    int ra = s*16 + (lane & 15);
    bool va = ra < N;
    short8 a[4];
    if (IN_F32) {
      const float* xin = (const float*)in_;
      #pragma unroll
      for (int kc = 0; kc < 4; ++kc) {
        short8 t = {0,0,0,0,0,0,0,0};
        if (va) {
          const float* p = xin + (size_t)ra*HDIM + kc*32 + krow;
          float4 lo4 = *(const float4*)p;
          float4 hi4 = *(const float4*)(p+4);
          t[0]=(short)f2bf(lo4.x); t[1]=(short)f2bf(lo4.y); t[2]=(short)f2bf(lo4.z); t[3]=(short)f2bf(lo4.w);
          t[4]=(short)f2bf(hi4.x); t[5]=(short)f2bf(hi4.y); t[6]=(short)f2bf(hi4.z); t[7]=(short)f2bf(hi4.w);
        }
        a[kc] = t;
      }
    } else {
      const ushort* hin = (const ushort*)in_;
      #pragma unroll
      for (int kc = 0; kc < 4; ++kc) {
        short8 t = {0,0,0,0,0,0,0,0};
        if (va) t = *(const short8*)(hin + (size_t)ra*HDIM + kc*32 + krow);
        a[kc] = t;
      }
    }
    f32x4 acc[8];
    #pragma unroll
    for (int nt = 0; nt < 8; ++nt) { acc[nt][0]=0.f; acc[nt][1]=0.f; acc[nt][2]=0.f; acc[nt][3]=0.f; }
    #pragma unroll
    for (int nt = 0; nt < 8; ++nt)
      #pragma unroll
      for (int kc = 0; kc < 4; ++kc)
        acc[nt] = __builtin_amdgcn_mfma_f32_16x16x32_bf16(a[kc], bfr[nt][kc], acc[nt], 0, 0, 0);

    int r0 = s*16 + (lane>>4)*4;
    #pragma unroll
    for (int nt = 0; nt < 8; ++nt) {
      int c = nt*16 + (lane&15);
      #pragma unroll
      for (int rg = 0; rg < 4; ++rg) {
        int rr = r0 + rg;
        if (rr < N) xw[(size_t)rr*HDIM + c] = f2bf(acc[nt][rg]);
      }
    }
  }
}

template<int IN_F32>
__global__ __launch_bounds__(256,1) void k_gemm(const void* __restrict__ in_, const float* __restrict__ W,
    ushort* __restrict__ xw, int N) {
  int wid = (blockIdx.x * blockDim.x + threadIdx.x) >> 6;
  int nw  = (gridDim.x * blockDim.x) >> 6;
  gemm_body<IN_F32>(in_, W, xw, N, wid, nw);
}

// ---------------- fused: layer-0 GEMM (1/4 of blocks) + CSR fill (3/4) ----------------
// Independent workloads; fill is fabric/scatter-bound, GEMM is compute-bound, so
// co-resident blocks overlap. Roles interleaved so each CU holds a mix.
__global__ __launch_bounds__(256,1) void k_fuse(const float* __restrict__ x, const float* __restrict__ W0,
    ushort* __restrict__ xw, int N,
    const int* __restrict__ src, const int* __restrict__ dst, int E,
    const float* __restrict__ dinv, const int* __restrict__ row_ptr, int* __restrict__ fill,
    int2* __restrict__ epack) {
  if ((blockIdx.x & 3) == 0) {
    int gb  = blockIdx.x >> 2;                       // gemm block index, 0..gridDim/4-1
    int ngb = gridDim.x >> 2;
    int wid = (gb * 256 + threadIdx.x) >> 6;
    int nw  = (ngb * 256) >> 6;
    gemm_body<1>((const void*)x, W0, xw, N, wid, nw);
  } else {
    int fb  = blockIdx.x - ((blockIdx.x + 3) >> 2);  // fill block index, 0..(3/4*gridDim)-1
    int nfb = gridDim.x - (gridDim.x >> 2);
    for (int e = fb*256 + (int)threadIdx.x; e < E; e += nfb*256) {
      int s = src[e], d = dst[e];
      int pos = row_ptr[d] + atomicAdd(&fill[d], 1);
      float cf = dinv[s] * dinv[d];
      epack[pos] = make_int2(s, __float_as_int(cf));
    }
  }
}

// ---------------- aggregation: one wave per node, 16 gathers in flight ----------------
__global__ __launch_bounds__(256) void k_agg(const uint* __restrict__ xwu, const int2* __restrict__ epack,
    const int* __restrict__ row_ptr, const float* __restrict__ dinv, const float* __restrict__ bias,
    uint* __restrict__ hu, int N) {
  int lane = threadIdx.x & 63;
  int n = blockIdx.x*4 + (threadIdx.x >> 6);
  if (n >= N) return;
  int e0 = row_ptr[n], e1 = row_ptr[n+1];
  float a0 = 0.f, a1 = 0.f;
  for (int base = e0; base < e1; base += 64) {
    int cnt = min(64, e1 - base);
    int2 myp = make_int2(0, 0);            // lanes >= cnt: src=0, coef=0 (harmless dummy)
    if (lane < cnt) myp = epack[base + lane];
    for (int j = 0; j < cnt; j += 16) {
      #pragma unroll
      for (int u = 0; u < 16; ++u) {
        int idx = j + u;
        int   sN = __shfl(myp.x, idx);
        float cf = __int_as_float(__shfl(myp.y, idx));
        uint v = xwu[(size_t)sN*64 + lane];
        a0 += cf * bflo(v);
        a1 += cf * bfhi(v);
      }
    }
  }
  float di = dinv[n]; float w = di*di;
  uint v = xwu[(size_t)n*64 + lane];
  a0 += w * bflo(v);
  a1 += w * bfhi(v);
  a0 += bias[lane*2];  a1 += bias[lane*2+1];
  a0 = fmaxf(a0, 0.f); a1 = fmaxf(a1, 0.f);
  uint o = ((uint)f2bf(a0)) | (((uint)f2bf(a1)) << 16);
  hu[(size_t)n*64 + lane] = o;
}

// ---------------- pooling: segmented accumulate (batch sorted) ----------------
__global__ __launch_bounds__(256) void k_pool(const uint* __restrict__ hu, const int* __restrict__ batch,
    float* __restrict__ psum, int N) {
  int lane = threadIdx.x & 63;
  int wave = threadIdx.x >> 6;
  int n0 = blockIdx.x*512 + wave*128;
  if (n0 >= N) return;
  int n1 = min(n0 + 128, N);
  float a0 = 0.f, a1 = 0.f;
  int gc = batch[n0];
  for (int n = n0; n < n1; ++n) {
    int g = batch[n];
    if (g != gc) {
      atomicAdd(&psum[gc*HDIM + lane*2],   a0);
      atomicAdd(&psum[gc*HDIM + lane*2+1], a1);
      a0 = 0.f; a1 = 0.f; gc = g;
    }
    uint v = hu[(size_t)n*64 + lane];
    a0 += bflo(v); a1 += bfhi(v);
  }
  atomicAdd(&psum[gc*HDIM + lane*2],   a0);
  atomicAdd(&psum[gc*HDIM + lane*2+1], a1);
}

// ---------------- graph sizes via binary search (batch sorted) ----------------
__global__ void k_bounds(const int* __restrict__ batch, int N, int G, float* __restrict__ inv_cnt) {
  __shared__ int bnd[256];
  int g = threadIdx.x;
  if (g <= G) {
    int lo = 0, hi = N;
    while (lo < hi) { int mid = (lo + hi) >> 1; if (batch[mid] < g) lo = mid + 1; else hi = mid; }
    bnd[g] = lo;
  }
  __syncthreads();
  if (g < G) {
    int c = bnd[g+1] - bnd[g];
    inv_cnt[g] = 1.0f / (float)max(c, 1);
  }
}

// ---------------- final linear ----------------
__global__ __launch_bounds__(256) void k_final(const float* __restrict__ psum, const float* __restrict__ inv_cnt,
    const float* __restrict__ Wlin, const float* __restrict__ blin, float* __restrict__ out, int G, int C) {
  int idx = blockIdx.x*256 + threadIdx.x;
  if (idx >= G*C) return;
  int g = idx / C, c = idx % C;
  float acc = 0.f;
  for (int k = 0; k < HDIM; ++k) acc += psum[g*HDIM + k] * Wlin[k*C + c];
  out[idx] = acc * inv_cnt[g] + blin[c];
}

extern "C" void kernel_launch(void* const* d_in, const int* in_sizes, int n_in,
                              void* d_out, int out_size, void* d_ws, size_t ws_size,
                              hipStream_t stream) {
  const float* x    = (const float*)d_in[0];
  const int*   ei   = (const int*)d_in[1];
  const int*   batch= (const int*)d_in[2];
  const float* W0   = (const float*)d_in[3];
  const float* b0   = (const float*)d_in[4];
  const float* W1   = (const float*)d_in[5];
  const float* b1   = (const float*)d_in[6];
  const float* W2   = (const float*)d_in[7];
  const float* b2   = (const float*)d_in[8];
  const float* Wlin = (const float*)d_in[9];
  const float* blin = (const float*)d_in[10];

  int N = in_sizes[0] / HDIM;
  int E = in_sizes[1] / 2;
  int C = in_sizes[10];
  int G = out_size / C;
  const int* src = ei;
  const int* dst = ei + E;

  char* ws = (char*)d_ws;
  size_t o = 0;
  auto alloc = [&](size_t bytes){ size_t r = o; o += (bytes + 511) & ~(size_t)511; return r; };
  size_t zbeg  = o;
  int*    degc    = (int*)   (ws + alloc((size_t)N*4));
  int*    fill    = (int*)   (ws + alloc((size_t)N*4));
  float*  psum    = (float*) (ws + alloc((size_t)G*HDIM*4));
  size_t zend  = o;
  float*  dinv    = (float*) (ws + alloc((size_t)N*4));
  int*    row_ptr = (int*)   (ws + alloc((size_t)(N+1)*4));
  float*  inv_cnt = (float*) (ws + alloc((size_t)G*4));
  int*    blocksum= (int*)   (ws + alloc((size_t)SCAN_NB*4));
  int*    blockoff= (int*)   (ws + alloc((size_t)SCAN_NB*4));
  int*    totalN  = (int*)   (ws + alloc(4));
  int2*   epack   = (int2*)  (ws + alloc((size_t)E*8));
  ushort* xw      = (ushort*)(ws + alloc((size_t)N*HDIM*2));
  ushort* hbuf    = (ushort*)(ws + alloc((size_t)N*HDIM*2));

  hipMemsetAsync(ws + zbeg, 0, zend - zbeg, stream);

  k_deg  <<<2048, 256, 0, stream>>>(dst, E, degc);
  k_dinv <<<(N+255)/256, 256, 0, stream>>>(degc, dinv, N);
  k_scanA<<<SCAN_NB, SCAN_TPB, 0, stream>>>(degc, N, blocksum);
  k_scanB<<<1, SCAN_NB, 0, stream>>>(blocksum, blockoff, totalN);
  k_scanC<<<SCAN_NB, SCAN_TPB, 0, stream>>>(degc, N, blockoff, totalN, row_ptr);
  k_bounds<<<1, 256, 0, stream>>>(batch, N, G, inv_cnt);

  // fused: layer-0 GEMM + CSR fill (independent; overlap compute with scatter)
  k_fuse<<<2048, 256, 0, stream>>>(x, W0, xw, N, src, dst, E, dinv, row_ptr, fill, epack);

  const int gemm_blocks = 512;
  const int agg_blocks  = (N + 3) / 4;

  k_agg<<<agg_blocks, 256, 0, stream>>>((const uint*)xw, epack, row_ptr, dinv, b0, (uint*)hbuf, N);
  // layer 1
  k_gemm<0><<<gemm_blocks, 256, 0, stream>>>((const void*)hbuf, W1, xw, N);
  k_agg<<<agg_blocks, 256, 0, stream>>>((const uint*)xw, epack, row_ptr, dinv, b1, (uint*)hbuf, N);
  // layer 2
  k_gemm<0><<<gemm_blocks, 256, 0, stream>>>((const void*)hbuf, W2, xw, N);
  k_agg<<<agg_blocks, 256, 0, stream>>>((const uint*)xw, epack, row_ptr, dinv, b2, (uint*)hbuf, N);

  k_pool<<<(N + 511)/512, 256, 0, stream>>>((const uint*)hbuf, batch, psum, N);
  k_final<<<(G*C + 255)/256, 256, 0, stream>>>(psum, inv_cnt, Wlin, blin, (float*)d_out, G, C);
}